// Round 24
// baseline (160.514 us; speedup 1.0000x reference)
//
#include <hip/hip_runtime.h>

// ---------------------------------------------------------------------------
// CausalSelfAttention: x@Wqkv+b -> split heads -> causal softmax attn -> proj
// B=4, T=2048, C=1024, H=16, hd=64.  All I/O fp32; internal compute bf16 MFMA.
// ---------------------------------------------------------------------------

typedef __attribute__((ext_vector_type(8))) short bf16x8;
typedef __attribute__((ext_vector_type(4))) float f32x4;

#define MFMA16(a, b, c) __builtin_amdgcn_mfma_f32_16x16x32_bf16(a, b, c, 0, 0, 0)

#define QK_SCALE 0.1803368801111244f   // 0.125 * log2(e), folded into Q at GEMM1

__device__ __forceinline__ unsigned short f2bf(float f) {
    union { float f; unsigned u; } v; v.f = f;
    unsigned r = v.u + 0x7fffu + ((v.u >> 16) & 1u);   // RNE
    return (unsigned short)(r >> 16);
}

// async global->LDS, 16B per lane (dest must be wave-linear: base + lane*16)
typedef __attribute__((address_space(1))) const unsigned int guint;
typedef __attribute__((address_space(3))) unsigned int luint;
__device__ __forceinline__ void gload16(const void* g, void* l) {
    __builtin_amdgcn_global_load_lds((guint*)g, (luint*)l, 16, 0, 0);
}

__device__ __forceinline__ float exp2_hw(float x) {
    float y;
    asm("v_exp_f32 %0, %1" : "=v"(y) : "v"(x));   // 2^x, single TRANS op
    return y;
}

__device__ __forceinline__ unsigned cvt_pk_bf16(float lo, float hi) {
    unsigned w;                                    // w[15:0]=bf16(lo) w[31:16]=bf16(hi)
    asm("v_cvt_pk_bf16_f32 %0, %1, %2" : "=v"(w) : "v"(lo), "v"(hi));
    return w;
}

// LDS tile swizzle for 64B rows (BK=32): slot chunk c of row r holds global
// 16B-chunk c ^ ((r>>1)&3) -> every 4-bank region serves 2 lanes (r11-proven).
__device__ __forceinline__ int swz_src_col(int off) {   // off = LDS byte offset
    return ((((off >> 4) & 3) ^ ((off >> 7) & 3)) << 3);   // shorts
}

// ---- fused prep: fp32->bf16 convert of x (4x float4/thread) + transposes --
// blocks [0,2048): conv; [2048,5120): Wqkv^T; [5120,6144): Wpr^T.
__global__ __launch_bounds__(256) void k_prep(
    const float* __restrict__ x, unsigned short* __restrict__ xb,
    const float* __restrict__ Wqkv, unsigned short* __restrict__ Wqt,
    const float* __restrict__ Wpr, unsigned short* __restrict__ Wpt) {
    __shared__ unsigned short tile[32][33];
    const int b = blockIdx.x;
    if (b < 2048) {
#pragma unroll
        for (int u = 0; u < 4; ++u) {
            int i = (b * 4 + u) * 256 + threadIdx.x;
            float4 v = reinterpret_cast<const float4*>(x)[i];
            ushort4 o;
            o.x = f2bf(v.x); o.y = f2bf(v.y); o.z = f2bf(v.z); o.w = f2bf(v.w);
            reinterpret_cast<ushort4*>(xb)[i] = o;
        }
        return;
    }
    const float* W; unsigned short* Wt; int K, N, idx;
    if (b < 5120) { W = Wqkv; Wt = Wqt; K = 1024; N = 3072; idx = b - 2048; }
    else          { W = Wpr;  Wt = Wpt; K = 1024; N = 1024; idx = b - 5120; }
    const int nb = N / 32;
    const int bn = (idx % nb) * 32, bk = (idx / nb) * 32;
    int tx = threadIdx.x & 31, ty = threadIdx.x >> 5;   // ty 0..7
#pragma unroll
    for (int i = 0; i < 32; i += 8)
        tile[ty + i][tx] = f2bf(W[(size_t)(bk + ty + i) * N + bn + tx]);
    __syncthreads();
#pragma unroll
    for (int i = 0; i < 32; i += 8)
        Wt[(size_t)(bn + ty + i) * K + bk + tx] = tile[tx][ty + i];
}

// ---- GEMM1: xb[8192][1024] @ Wqkv -> Q(scaled),K (B,H,T,hd), permuted V^T
// BM=128 x BN=256, BK=64, 512 threads / 8 waves (2Mx4N), wave-tile 64x64.
// Ring-3 LDS (3 x 48KB), counted vmcnt(6) + single s_barrier per K-iter.
// XCD-grouped remap (T1).  No setprio (m190).  r20-r23 proven.
// Key permutation per 64-token chunk: c -> (c&0x60)|((c&15)<<1)|((c>>4)&1)
__global__ __launch_bounds__(512, 2) void k_gemm_qkv(
    const unsigned short* __restrict__ A,    // [8192][1024] bf16
    const unsigned short* __restrict__ Bt,   // [3072][1024] bf16 (W^T)
    const float* __restrict__ bias,          // [3072]
    unsigned short* __restrict__ Qo,         // [64][2048][64]  (pre-scaled)
    unsigned short* __restrict__ Ko,         // [64][2048][64]
    unsigned short* __restrict__ Vto)        // [64][64][2048] (key-permuted)
{
    constexpr int K = 1024;
    __shared__ alignas(16) char smem[147456];   // ring 3 x (A 16KB | B 32KB) ∪ Ep
    const int tid = threadIdx.x;
    const int wave = tid >> 6, lane = tid & 63;
    const int wr = wave >> 2, wc = wave & 3;    // 2M x 4N
    const int lrow = lane & 15, lkg = lane >> 4;
    // XCD-grouped remap: 768 = 8 xcd x 8 bm-local x 12 bn
    const int bid = blockIdx.x;
    const int xcd = bid & 7, sq = bid >> 3;
    const int bm = (xcd * 8 + (sq & 7)) * 128;
    const int bn = (sq >> 3) * 256;

    const int scol = (((tid & 7) ^ ((tid >> 3) & 7)) << 3);
    const int r0 = tid >> 3;
    const unsigned short* gA[2];
    const unsigned short* gB[4];
#pragma unroll
    for (int i = 0; i < 2; ++i)
        gA[i] = A + (size_t)(bm + i * 64 + r0) * K + scol;
#pragma unroll
    for (int i = 0; i < 4; ++i)
        gB[i] = Bt + (size_t)(bn + i * 64 + r0) * K + scol;

    f32x4 acc[4][4] = {};

#define GSTAGE(kt_, slot_)                                          \
    do {                                                            \
        char* ba_ = smem + (slot_) * 49152;                         \
        gload16(gA[0] + (kt_), ba_ + tid * 16);                     \
        gload16(gA[1] + (kt_), ba_ + 8192 + tid * 16);              \
        gload16(gB[0] + (kt_), ba_ + 16384 + tid * 16);             \
        gload16(gB[1] + (kt_), ba_ + 24576 + tid * 16);             \
        gload16(gB[2] + (kt_), ba_ + 32768 + tid * 16);             \
        gload16(gB[3] + (kt_), ba_ + 40960 + tid * 16);             \
    } while (0)

    GSTAGE(0, 0);
    GSTAGE(64, 1);
    int cs = 0;                                  // slot of current tile
    for (int t = 0; t < 16; ++t) {
        if (t < 15) asm volatile("s_waitcnt vmcnt(6)" ::: "memory");
        else        asm volatile("s_waitcnt vmcnt(0)" ::: "memory");
        __builtin_amdgcn_s_barrier();
        __builtin_amdgcn_sched_barrier(0);
        if (t + 2 < 16) {
            int ns = cs + 2; if (ns >= 3) ns -= 3;
            GSTAGE((t + 2) * 64, ns);
        }

        const char* Ab = smem + cs * 49152;
        const char* Bb = Ab + 16384;
        bf16x8 af[4][2], bfr[4][2];
#pragma unroll
        for (int m = 0; m < 4; ++m) {
            int R = wr * 64 + m * 16 + lrow;
#pragma unroll
            for (int k = 0; k < 2; ++k)
                af[m][k] = *reinterpret_cast<const bf16x8*>(
                    Ab + R * 128 + (((k * 4 + lkg) ^ (R & 7)) << 4));
        }
#pragma unroll
        for (int n = 0; n < 4; ++n) {
            int R = wc * 64 + n * 16 + lrow;
#pragma unroll
            for (int k = 0; k < 2; ++k)
                bfr[n][k] = *reinterpret_cast<const bf16x8*>(
                    Bb + R * 128 + (((k * 4 + lkg) ^ (R & 7)) << 4));
        }
#pragma unroll
        for (int m = 0; m < 4; ++m)
#pragma unroll
            for (int n = 0; n < 4; ++n) {
                acc[m][n] = MFMA16(af[m][0], bfr[n][0], acc[m][n]);
                acc[m][n] = MFMA16(af[m][1], bfr[n][1], acc[m][n]);
            }
        ++cs; if (cs == 3) cs = 0;
    }
#undef GSTAGE
    __syncthreads();    // all waves done; ring dead -> Ep may alias

    // ---- epilogue (single pass; all 8 waves write disjoint regions) ----
    const int which = bn >> 10;          // 0=Q 1=K 2=V (256 | 1024 exact)
    const int h0 = (bn & 1023) >> 6;     // first head of this 256-col tile
    const int bq = bm >> 11;             // batch index
    const int t0 = bm & 2047;            // token base (128 rows)
    const float qs = (which == 0) ? QK_SCALE : 1.0f;
    unsigned short* Ep = (unsigned short*)smem;

    if (which != 2) {
        // Ep [128 t][258 c]
#pragma unroll
        for (int m = 0; m < 4; ++m) {
            int trow = wr * 64 + m * 16 + lkg * 4;
#pragma unroll
            for (int n = 0; n < 4; ++n) {
                int cl = wc * 64 + n * 16 + lrow;
                float bia = bias[bn + cl];
#pragma unroll
                for (int r = 0; r < 4; ++r)
                    Ep[(trow + r) * 258 + cl] = f2bf((acc[m][n][r] + bia) * qs);
            }
        }
        __syncthreads();
        const int chunk = tid & 31, rbase = tid >> 5;   // 32 col-chunks x 16 rows
        const int head = h0 + (chunk >> 3), d0 = (chunk & 7) * 8;
        unsigned short* dst = (which == 0 ? Qo : Ko) +
            (size_t)((bq * 16 + head) * 2048 + t0) * 64 + d0;
#pragma unroll
        for (int s = 0; s < 8; ++s) {
            int row = s * 16 + rbase;
            bf16x8 v = *reinterpret_cast<const bf16x8*>(&Ep[row * 258 + chunk * 8]);
            *reinterpret_cast<bf16x8*>(dst + (size_t)row * 64) = v;
        }
    } else {
        // Ep [256 c][130 perm-t]
#pragma unroll
        for (int m = 0; m < 4; ++m) {
            int tl0 = wr * 64 + m * 16 + lkg * 4;
#pragma unroll
            for (int n = 0; n < 4; ++n) {
                int cl = wc * 64 + n * 16 + lrow;
                float bia = bias[bn + cl];
#pragma unroll
                for (int r = 0; r < 4; ++r) {
                    int tl = tl0 + r;
                    int pt = (tl & 0x60) | ((tl & 15) << 1) | ((tl >> 4) & 1);
                    Ep[cl * 130 + pt] = f2bf(acc[m][n][r] + bia);
                }
            }
        }
        __syncthreads();
        const int chunkt = tid & 15, crow = tid >> 4;   // 16 pt-chunks x 32 c-rows
#pragma unroll
        for (int s = 0; s < 8; ++s) {
            int cl = s * 32 + crow;                      // 0..255
            bf16x8 v = *reinterpret_cast<const bf16x8*>(&Ep[cl * 130 + chunkt * 8]);
            int bh = bq * 16 + h0 + (cl >> 6);
            size_t addr = ((size_t)(bh * 64 + (cl & 63)) * 2048) + t0 + chunkt * 8;
            *reinterpret_cast<bf16x8*>(Vto + addr) = v;
        }
    }
}

// ---- flash attention (r22-proven: ones-MFMA row-sums, setprio kept) -------
__global__ __launch_bounds__(256, 2) void k_attn(
    const unsigned short* __restrict__ Q,   // [64][2048][64] pre-scaled
    const unsigned short* __restrict__ Kg,  // [64][2048][64]
    const unsigned short* __restrict__ Vt,  // [64][64][2048] key-permuted
    unsigned short* __restrict__ Y)         // [4][2048][1024] bf16
{
    __shared__ alignas(16) unsigned short Ks[2][4096];   // [64 key][64 hd] swz
    __shared__ alignas(16) unsigned short Vs[2][4096];   // [64 hd][64 key] swz
    __shared__ unsigned int Pu[4][32][36];               // packed P per wave
    const int tid = threadIdx.x;
    const int wave = tid >> 6, lane = tid & 63;
    const int lrow = lane & 15, lkg = lane >> 4;
    const int bh = blockIdx.x & 63;              // head id; same head -> same XCD
    const int s = (blockIdx.x >> 6) & 3;
    const int band = blockIdx.x >> 8;            // 0..3
    const int j = (band == 0) ? 15 - s : (band == 1) ? 8 + s : (band == 2) ? 7 - s : s;
    const int qt = 4 * j + wave;                 // this wave's 32-row q tile
    const int q0 = qt * 32;
    const int qmax = q0 + 31;
    const int nt = 2 * j + 2;                    // block-uniform chunk count
    const int b = bh >> 4, hh = bh & 15;

    const unsigned short* Qh = Q + (size_t)bh * 2048 * 64;
    const unsigned short* Kh = Kg + (size_t)bh * 2048 * 64;
    const unsigned short* Vh = Vt + (size_t)bh * 64 * 2048;

    const int srow = tid >> 3;                   // 0..31 (+32 on 2nd issue)
    const int swz = ((tid & 7) ^ (srow & 7)) << 3;
    const unsigned short* gK = Kh + (size_t)srow * 64 + swz;
    const unsigned short* gV = Vh + (size_t)srow * 2048 + swz;
    char* dK0 = (char*)&Ks[0][0] + tid * 16;
    char* dV0 = (char*)&Vs[0][0] + tid * 16;

    bf16x8 aq[2][2];
#pragma unroll
    for (int h = 0; h < 2; ++h)
#pragma unroll
        for (int ks = 0; ks < 2; ++ks)
            aq[h][ks] = *reinterpret_cast<const bf16x8*>(
                &Qh[(size_t)(q0 + h * 16 + lrow) * 64 + ks * 32 + lkg * 8]);

    const bf16x8 ONES = { (short)0x3F80, (short)0x3F80, (short)0x3F80, (short)0x3F80,
                          (short)0x3F80, (short)0x3F80, (short)0x3F80, (short)0x3F80 };

    f32x4 acc[2][4] = {};
    f32x4 accl[2] = {};                          // row sums of P (ones-MFMA)

#define STAGE(kb_, bufn_)                                           \
    do {                                                            \
        const unsigned short* k0_ = gK + (kb_) * 64;                \
        const unsigned short* v0_ = gV + (kb_);                     \
        char* dk_ = dK0 + (bufn_) * 8192;                           \
        char* dv_ = dV0 + (bufn_) * 8192;                           \
        gload16(k0_, dk_);                                          \
        gload16(k0_ + 2048, dk_ + 4096);                            \
        gload16(v0_, dv_);                                          \
        gload16(v0_ + 65536, dv_ + 4096);                           \
    } while (0)

    STAGE(0, 0);
    int buf = 0;

    for (int t = 0; t < nt; ++t) {
        asm volatile("s_waitcnt vmcnt(0)" ::: "memory");
        __builtin_amdgcn_s_barrier();          // buf landed + buf^1 free
        __builtin_amdgcn_sched_barrier(0);
        if (t + 1 < nt) STAGE((t + 1) * 64, buf ^ 1);

        const int kb = t * 64;
        if (kb <= qmax) {                      // wave-uniform causal skip
            const char* kbase = (const char*)&Ks[buf][0];
            const char* vbase = (const char*)&Vs[buf][0];

            // S = Q K^T  (16 MFMAs), K frags from swizzled LDS
            f32x4 s_[2][4] = {};
            __builtin_amdgcn_s_setprio(1);
#pragma unroll
            for (int sub = 0; sub < 4; ++sub) {
                int krow = sub * 16 + lrow;
                bf16x8 kf0 = *reinterpret_cast<const bf16x8*>(
                    kbase + krow * 128 + ((lkg ^ (krow & 7)) << 4));
                bf16x8 kf1 = *reinterpret_cast<const bf16x8*>(
                    kbase + krow * 128 + (((4 + lkg) ^ (krow & 7)) << 4));
                s_[0][sub] = MFMA16(aq[0][0], kf0, s_[0][sub]);
                s_[0][sub] = MFMA16(aq[0][1], kf1, s_[0][sub]);
                s_[1][sub] = MFMA16(aq[1][0], kf0, s_[1][sub]);
                s_[1][sub] = MFMA16(aq[1][1], kf1, s_[1][sub]);
            }
            __builtin_amdgcn_s_setprio(0);

            // causal mask (diagonal-crossing chunks only), then exp2
            const bool need_mask = (kb + 64 > q0);
#pragma unroll
            for (int h = 0; h < 2; ++h)
#pragma unroll
                for (int sub = 0; sub < 4; ++sub)
#pragma unroll
                    for (int r = 0; r < 4; ++r) {
                        float v = s_[h][sub][r];
                        if (need_mask) {
                            int key = kb + sub * 16 + lrow;
                            int q = q0 + h * 16 + lkg * 4 + r;
                            v = (key <= q) ? v : -1e30f;
                        }
                        s_[h][sub][r] = exp2_hw(v);   // masked -> 0
                    }

            // pack P (bf16 pairs, key-permuted order); no VALU row-sum
#pragma unroll
            for (int h = 0; h < 2; ++h) {
                int prow = h * 16 + lkg * 4;
#pragma unroll
                for (int r = 0; r < 4; ++r) {
                    Pu[wave][prow + r][lrow]      = cvt_pk_bf16(s_[h][0][r], s_[h][1][r]);
                    Pu[wave][prow + r][16 + lrow] = cvt_pk_bf16(s_[h][2][r], s_[h][3][r]);
                }
            }

            // P fragments (per-wave, same-wave RAW -> no barrier needed)
            bf16x8 pf[2][2];
#pragma unroll
            for (int h = 0; h < 2; ++h)
#pragma unroll
                for (int kc = 0; kc < 2; ++kc)
                    pf[h][kc] = *reinterpret_cast<const bf16x8*>(
                        &Pu[wave][h * 16 + lrow][kc * 16 + lkg * 4]);

            // PV (16 MFMAs) + row-sum (4 MFMAs), V frags from swizzled LDS
            __builtin_amdgcn_s_setprio(1);
#pragma unroll
            for (int tt = 0; tt < 4; ++tt) {
                int vrow = tt * 16 + lrow;
                bf16x8 vf0 = *reinterpret_cast<const bf16x8*>(
                    vbase + vrow * 128 + ((lkg ^ (vrow & 7)) << 4));
                bf16x8 vf1 = *reinterpret_cast<const bf16x8*>(
                    vbase + vrow * 128 + (((4 + lkg) ^ (vrow & 7)) << 4));
                acc[0][tt] = MFMA16(pf[0][0], vf0, acc[0][tt]);
                acc[0][tt] = MFMA16(pf[0][1], vf1, acc[0][tt]);
                acc[1][tt] = MFMA16(pf[1][0], vf0, acc[1][tt]);
                acc[1][tt] = MFMA16(pf[1][1], vf1, acc[1][tt]);
            }
#pragma unroll
            for (int h = 0; h < 2; ++h) {
                accl[h] = MFMA16(pf[h][0], ONES, accl[h]);
                accl[h] = MFMA16(pf[h][1], ONES, accl[h]);
            }
            __builtin_amdgcn_s_setprio(0);
        }

        buf ^= 1;
    }
#undef STAGE

    // epilogue: normalize (row sums already in accl; cols broadcast), store
#pragma unroll
    for (int h = 0; h < 2; ++h) {
        float inv[4];
#pragma unroll
        for (int r = 0; r < 4; ++r)
            inv[r] = 1.0f / accl[h][r];
#pragma unroll
        for (int t = 0; t < 4; ++t)
#pragma unroll
            for (int r = 0; r < 4; ++r) {
                int q = q0 + h * 16 + lkg * 4 + r;
                size_t idx = ((size_t)b * 2048 + q) * 1024 + hh * 64 + t * 16 + lrow;
                Y[idx] = f2bf(acc[h][t][r] * inv[r]);
            }
    }
}

// ---- GEMM2: Y[8192][1024] @ Wpr -> out fp32 + bias -----------------------
// Small-slot ring-3: BM=BN=128, BK=32, 256 threads / 4 waves (2Mx2N),
// slot 16KB (A 8 + B 8), ring 48KB -> 3 blocks/CU capacity; grid 512 = 2/CU
// exact (r23 had 1 block/CU single-generation: no overlap of fill/drain).
// Ledger: 4 loads/tile, distance-2 prefetch -> vmcnt(4), tail 4->0.
// Staging map + swizzle + fragment reads + Ep2 epilogue are r12-proven.
__global__ __launch_bounds__(256, 2) void k_gemm_proj(
    const unsigned short* __restrict__ A,    // [8192][1024] bf16
    const unsigned short* __restrict__ Bt,   // [1024][1024] bf16 (W^T)
    const float* __restrict__ bias,          // [1024]
    float* __restrict__ out)                 // [8192][1024] fp32
{
    constexpr int K = 1024;
    __shared__ alignas(16) char smem[49152];   // ring 3 x (A 8KB | B 8KB) ∪ Ep2
    float* Ep2 = (float*)smem;                 // [64][129] (33KB, aliases ring)
    const int tid = threadIdx.x;
    const int wave = tid >> 6, lane = tid & 63;
    const int wr = wave >> 1, wc = wave & 1;
    const int lrow = lane & 15, lkg = lane >> 4;
    // XCD-grouped remap: 512 = 8 xcd x 8 bm-local x 8 bn
    const int bid = blockIdx.x;
    const int xcd = bid & 7, sq = bid >> 3;
    const int bm = (xcd * 8 + (sq & 7)) * 128;
    const int bn = (sq >> 3) * 128;

    const int off0 = tid * 16, off1 = off0 + 4096;
    const unsigned short* gA0 = A + (size_t)(bm + (off0 >> 6)) * K + swz_src_col(off0);
    const unsigned short* gA1 = A + (size_t)(bm + (off1 >> 6)) * K + swz_src_col(off1);
    const unsigned short* gB0 = Bt + (size_t)(bn + (off0 >> 6)) * K + swz_src_col(off0);
    const unsigned short* gB1 = Bt + (size_t)(bn + (off1 >> 6)) * K + swz_src_col(off1);

    f32x4 acc[4][4] = {};

#define GSTAGE(kt_, slot_)                                          \
    do {                                                            \
        char* ba_ = smem + (slot_) * 16384;                         \
        gload16(gA0 + (kt_), ba_ + off0);                           \
        gload16(gA1 + (kt_), ba_ + off1);                           \
        gload16(gB0 + (kt_), ba_ + 8192 + off0);                    \
        gload16(gB1 + (kt_), ba_ + 8192 + off1);                    \
    } while (0)

    GSTAGE(0, 0);
    GSTAGE(32, 1);
    int cs = 0;                                  // slot of current tile
    for (int t = 0; t < 32; ++t) {
        if (t < 31) asm volatile("s_waitcnt vmcnt(4)" ::: "memory");
        else        asm volatile("s_waitcnt vmcnt(0)" ::: "memory");
        __builtin_amdgcn_s_barrier();
        __builtin_amdgcn_sched_barrier(0);
        if (t + 2 < 32) {
            int ns = cs + 2; if (ns >= 3) ns -= 3;
            GSTAGE((t + 2) * 32, ns);
        }

        const char* Asb = smem + cs * 16384;
        const char* Bsb = Asb + 8192;
        bf16x8 af[4], bfr[4];
#pragma unroll
        for (int m = 0; m < 4; ++m) {
            int R = wr * 64 + m * 16 + lrow;
            af[m] = *reinterpret_cast<const bf16x8*>(
                Asb + R * 64 + ((lkg ^ ((R >> 1) & 3)) << 4));
        }
#pragma unroll
        for (int n = 0; n < 4; ++n) {
            int R = wc * 64 + n * 16 + lrow;
            bfr[n] = *reinterpret_cast<const bf16x8*>(
                Bsb + R * 64 + ((lkg ^ ((R >> 1) & 3)) << 4));
        }
#pragma unroll
        for (int m = 0; m < 4; ++m)
#pragma unroll
            for (int n = 0; n < 4; ++n)
                acc[m][n] = MFMA16(af[m], bfr[n], acc[m][n]);
        ++cs; if (cs == 3) cs = 0;
    }
#undef GSTAGE

    // ---- epilogue: two 64-row passes (Ep2 aliases ring; r12-proven) ----
    const int chunk = tid >> 3;        // 0..31 (16B col chunk)
    const int r8 = tid & 7;
#pragma unroll
    for (int p = 0; p < 2; ++p) {
        __syncthreads();               // ring dead / Ep2 pass boundary
        if (wr == p) {
#pragma unroll
            for (int m = 0; m < 4; ++m)
#pragma unroll
                for (int n = 0; n < 4; ++n) {
                    int cl = wc * 64 + n * 16 + lrow;
                    float bia = bias[bn + cl];
#pragma unroll
                    for (int r = 0; r < 4; ++r)
                        Ep2[(m * 16 + lkg * 4 + r) * 129 + cl] = acc[m][n][r] + bia;
                }
        }
        __syncthreads();
#pragma unroll
        for (int s = 0; s < 8; ++s) {
            int row = r8 * 8 + s;
            float4 v = *reinterpret_cast<const float4*>(&Ep2[row * 129 + chunk * 4]);
            *reinterpret_cast<float4*>(&out[(size_t)(bm + p * 64 + row) * 1024 + bn + chunk * 4]) = v;
        }
    }
}

extern "C" void kernel_launch(void* const* d_in, const int* in_sizes, int n_in,
                              void* d_out, int out_size, void* d_ws, size_t ws_size,
                              hipStream_t stream) {
    const float* x    = (const float*)d_in[0];   // [4,2048,1024]
    const float* Wqkv = (const float*)d_in[1];   // [1024,3072]
    const float* bqkv = (const float*)d_in[2];   // [3072]
    const float* Wpr  = (const float*)d_in[3];   // [1024,1024]
    const float* bpr  = (const float*)d_in[4];   // [1024]
    float* out = (float*)d_out;

    char* ws = (char*)d_ws;
    unsigned short* xb  = (unsigned short*)(ws);                  // 16.78 MB (reused as Y)
    unsigned short* Wqt = (unsigned short*)(ws + 16777216);       //  6.29 MB
    unsigned short* Wpt = (unsigned short*)(ws + 23068672);       //  2.10 MB
    unsigned short* Qb  = (unsigned short*)(ws + 25165824);       // 16.78 MB
    unsigned short* Kb  = (unsigned short*)(ws + 41943040);       // 16.78 MB
    unsigned short* Vt  = (unsigned short*)(ws + 58720256);       // 16.78 MB
    unsigned short* Y   = xb;   // xb dead after GEMM1

    k_prep<<<6144, 256, 0, stream>>>(x, xb, Wqkv, Wqt, Wpr, Wpt);
    k_gemm_qkv<<<768, 512, 0, stream>>>(xb, Wqt, bqkv, Qb, Kb, Vt);
    k_attn<<<1024, 256, 0, stream>>>(Qb, Kb, Vt, Y);
    k_gemm_proj<<<512, 256, 0, stream>>>(Y, Wpt, bpr, out);
}

// Round 26
// 155.121 us; speedup vs baseline: 1.0348x; 1.0348x over previous
//
#include <hip/hip_runtime.h>

// ---------------------------------------------------------------------------
// CausalSelfAttention: x@Wqkv+b -> split heads -> causal softmax attn -> proj
// B=4, T=2048, C=1024, H=16, hd=64.  All I/O fp32; internal compute bf16 MFMA.
// ---------------------------------------------------------------------------

typedef __attribute__((ext_vector_type(8))) short bf16x8;
typedef __attribute__((ext_vector_type(4))) float f32x4;

#define MFMA16(a, b, c) __builtin_amdgcn_mfma_f32_16x16x32_bf16(a, b, c, 0, 0, 0)

#define QK_SCALE 0.1803368801111244f   // 0.125 * log2(e), folded into Q at GEMM1

__device__ __forceinline__ unsigned short f2bf(float f) {
    union { float f; unsigned u; } v; v.f = f;
    unsigned r = v.u + 0x7fffu + ((v.u >> 16) & 1u);   // RNE
    return (unsigned short)(r >> 16);
}

// async global->LDS, 16B per lane (dest must be wave-linear: base + lane*16)
typedef __attribute__((address_space(1))) const unsigned int guint;
typedef __attribute__((address_space(3))) unsigned int luint;
__device__ __forceinline__ void gload16(const void* g, void* l) {
    __builtin_amdgcn_global_load_lds((guint*)g, (luint*)l, 16, 0, 0);
}

__device__ __forceinline__ float exp2_hw(float x) {
    float y;
    asm("v_exp_f32 %0, %1" : "=v"(y) : "v"(x));   // 2^x, single TRANS op
    return y;
}

__device__ __forceinline__ unsigned cvt_pk_bf16(float lo, float hi) {
    unsigned w;                                    // w[15:0]=bf16(lo) w[31:16]=bf16(hi)
    asm("v_cvt_pk_bf16_f32 %0, %1, %2" : "=v"(w) : "v"(lo), "v"(hi));
    return w;
}

// ---- fused prep: fp32->bf16 convert of x (4x float4/thread) + transposes --
// blocks [0,2048): conv; [2048,5120): Wqkv^T; [5120,6144): Wpr^T.
__global__ __launch_bounds__(256) void k_prep(
    const float* __restrict__ x, unsigned short* __restrict__ xb,
    const float* __restrict__ Wqkv, unsigned short* __restrict__ Wqt,
    const float* __restrict__ Wpr, unsigned short* __restrict__ Wpt) {
    __shared__ unsigned short tile[32][33];
    const int b = blockIdx.x;
    if (b < 2048) {
#pragma unroll
        for (int u = 0; u < 4; ++u) {
            int i = (b * 4 + u) * 256 + threadIdx.x;
            float4 v = reinterpret_cast<const float4*>(x)[i];
            ushort4 o;
            o.x = f2bf(v.x); o.y = f2bf(v.y); o.z = f2bf(v.z); o.w = f2bf(v.w);
            reinterpret_cast<ushort4*>(xb)[i] = o;
        }
        return;
    }
    const float* W; unsigned short* Wt; int K, N, idx;
    if (b < 5120) { W = Wqkv; Wt = Wqt; K = 1024; N = 3072; idx = b - 2048; }
    else          { W = Wpr;  Wt = Wpt; K = 1024; N = 1024; idx = b - 5120; }
    const int nb = N / 32;
    const int bn = (idx % nb) * 32, bk = (idx / nb) * 32;
    int tx = threadIdx.x & 31, ty = threadIdx.x >> 5;   // ty 0..7
#pragma unroll
    for (int i = 0; i < 32; i += 8)
        tile[ty + i][tx] = f2bf(W[(size_t)(bk + ty + i) * N + bn + tx]);
    __syncthreads();
#pragma unroll
    for (int i = 0; i < 32; i += 8)
        Wt[(size_t)(bn + ty + i) * K + bk + tx] = tile[tx][ty + i];
}

// ---- GEMM common geometry (r20-r23 proven) --------------------------------
// BM=128 x BN=256, BK=64, 512 threads / 8 waves (2Mx4N), wave-tile 64x64.
// Ring-3 LDS (3 x 48KB), counted vmcnt(6) + single s_barrier per K-iter.
// XCD-grouped block remap (T1): each XCD owns 8 contiguous bm panels.
// No setprio in GEMMs (m190: null-to-negative in lockstep loops).

// ---- GEMM1: xb[8192][1024] @ Wqkv -> Q(scaled),K (B,H,T,hd), permuted V^T
// Key permutation per 64-token chunk: c -> (c&0x60)|((c&15)<<1)|((c>>4)&1)
__global__ __launch_bounds__(512, 2) void k_gemm_qkv(
    const unsigned short* __restrict__ A,    // [8192][1024] bf16
    const unsigned short* __restrict__ Bt,   // [3072][1024] bf16 (W^T)
    const float* __restrict__ bias,          // [3072]
    unsigned short* __restrict__ Qo,         // [64][2048][64]  (pre-scaled)
    unsigned short* __restrict__ Ko,         // [64][2048][64]
    unsigned short* __restrict__ Vto)        // [64][64][2048] (key-permuted)
{
    constexpr int K = 1024;
    __shared__ alignas(16) char smem[147456];   // ring 3 x (A 16KB | B 32KB) ∪ Ep
    const int tid = threadIdx.x;
    const int wave = tid >> 6, lane = tid & 63;
    const int wr = wave >> 2, wc = wave & 3;    // 2M x 4N
    const int lrow = lane & 15, lkg = lane >> 4;
    // XCD-grouped remap: 768 = 8 xcd x 8 bm-local x 12 bn
    const int bid = blockIdx.x;
    const int xcd = bid & 7, sq = bid >> 3;
    const int bm = (xcd * 8 + (sq & 7)) * 128;
    const int bn = (sq >> 3) * 256;

    const int scol = (((tid & 7) ^ ((tid >> 3) & 7)) << 3);
    const int r0 = tid >> 3;
    const unsigned short* gA[2];
    const unsigned short* gB[4];
#pragma unroll
    for (int i = 0; i < 2; ++i)
        gA[i] = A + (size_t)(bm + i * 64 + r0) * K + scol;
#pragma unroll
    for (int i = 0; i < 4; ++i)
        gB[i] = Bt + (size_t)(bn + i * 64 + r0) * K + scol;

    f32x4 acc[4][4] = {};

#define GSTAGE(kt_, slot_)                                          \
    do {                                                            \
        char* ba_ = smem + (slot_) * 49152;                         \
        gload16(gA[0] + (kt_), ba_ + tid * 16);                     \
        gload16(gA[1] + (kt_), ba_ + 8192 + tid * 16);              \
        gload16(gB[0] + (kt_), ba_ + 16384 + tid * 16);             \
        gload16(gB[1] + (kt_), ba_ + 24576 + tid * 16);             \
        gload16(gB[2] + (kt_), ba_ + 32768 + tid * 16);             \
        gload16(gB[3] + (kt_), ba_ + 40960 + tid * 16);             \
    } while (0)

    GSTAGE(0, 0);
    GSTAGE(64, 1);
    int cs = 0;                                  // slot of current tile
    for (int t = 0; t < 16; ++t) {
        if (t < 15) asm volatile("s_waitcnt vmcnt(6)" ::: "memory");
        else        asm volatile("s_waitcnt vmcnt(0)" ::: "memory");
        __builtin_amdgcn_s_barrier();
        __builtin_amdgcn_sched_barrier(0);
        if (t + 2 < 16) {
            int ns = cs + 2; if (ns >= 3) ns -= 3;
            GSTAGE((t + 2) * 64, ns);
        }

        const char* Ab = smem + cs * 49152;
        const char* Bb = Ab + 16384;
        bf16x8 af[4][2], bfr[4][2];
#pragma unroll
        for (int m = 0; m < 4; ++m) {
            int R = wr * 64 + m * 16 + lrow;
#pragma unroll
            for (int k = 0; k < 2; ++k)
                af[m][k] = *reinterpret_cast<const bf16x8*>(
                    Ab + R * 128 + (((k * 4 + lkg) ^ (R & 7)) << 4));
        }
#pragma unroll
        for (int n = 0; n < 4; ++n) {
            int R = wc * 64 + n * 16 + lrow;
#pragma unroll
            for (int k = 0; k < 2; ++k)
                bfr[n][k] = *reinterpret_cast<const bf16x8*>(
                    Bb + R * 128 + (((k * 4 + lkg) ^ (R & 7)) << 4));
        }
#pragma unroll
        for (int m = 0; m < 4; ++m)
#pragma unroll
            for (int n = 0; n < 4; ++n) {
                acc[m][n] = MFMA16(af[m][0], bfr[n][0], acc[m][n]);
                acc[m][n] = MFMA16(af[m][1], bfr[n][1], acc[m][n]);
            }
        ++cs; if (cs == 3) cs = 0;
    }
#undef GSTAGE
    __syncthreads();    // all waves done; ring dead -> Ep may alias

    // ---- epilogue (single pass; all 8 waves write disjoint regions) ----
    const int which = bn >> 10;          // 0=Q 1=K 2=V (256 | 1024 exact)
    const int h0 = (bn & 1023) >> 6;     // first head of this 256-col tile
    const int bq = bm >> 11;             // batch index
    const int t0 = bm & 2047;            // token base (128 rows)
    const float qs = (which == 0) ? QK_SCALE : 1.0f;
    unsigned short* Ep = (unsigned short*)smem;

    if (which != 2) {
        // Ep [128 t][258 c]
#pragma unroll
        for (int m = 0; m < 4; ++m) {
            int trow = wr * 64 + m * 16 + lkg * 4;
#pragma unroll
            for (int n = 0; n < 4; ++n) {
                int cl = wc * 64 + n * 16 + lrow;
                float bia = bias[bn + cl];
#pragma unroll
                for (int r = 0; r < 4; ++r)
                    Ep[(trow + r) * 258 + cl] = f2bf((acc[m][n][r] + bia) * qs);
            }
        }
        __syncthreads();
        const int chunk = tid & 31, rbase = tid >> 5;   // 32 col-chunks x 16 rows
        const int head = h0 + (chunk >> 3), d0 = (chunk & 7) * 8;
        unsigned short* dst = (which == 0 ? Qo : Ko) +
            (size_t)((bq * 16 + head) * 2048 + t0) * 64 + d0;
#pragma unroll
        for (int s = 0; s < 8; ++s) {
            int row = s * 16 + rbase;
            bf16x8 v = *reinterpret_cast<const bf16x8*>(&Ep[row * 258 + chunk * 8]);
            *reinterpret_cast<bf16x8*>(dst + (size_t)row * 64) = v;
        }
    } else {
        // Ep [256 c][130 perm-t]
#pragma unroll
        for (int m = 0; m < 4; ++m) {
            int tl0 = wr * 64 + m * 16 + lkg * 4;
#pragma unroll
            for (int n = 0; n < 4; ++n) {
                int cl = wc * 64 + n * 16 + lrow;
                float bia = bias[bn + cl];
#pragma unroll
                for (int r = 0; r < 4; ++r) {
                    int tl = tl0 + r;
                    int pt = (tl & 0x60) | ((tl & 15) << 1) | ((tl >> 4) & 1);
                    Ep[cl * 130 + pt] = f2bf(acc[m][n][r] + bia);
                }
            }
        }
        __syncthreads();
        const int chunkt = tid & 15, crow = tid >> 4;   // 16 pt-chunks x 32 c-rows
#pragma unroll
        for (int s = 0; s < 8; ++s) {
            int cl = s * 32 + crow;                      // 0..255
            bf16x8 v = *reinterpret_cast<const bf16x8*>(&Ep[cl * 130 + chunkt * 8]);
            int bh = bq * 16 + h0 + (cl >> 6);
            size_t addr = ((size_t)(bh * 64 + (cl & 63)) * 2048) + t0 + chunkt * 8;
            *reinterpret_cast<bf16x8*>(Vto + addr) = v;
        }
    }
}

// ---- flash attention (r22-proven: ones-MFMA row-sums, setprio kept) -------
__global__ __launch_bounds__(256, 2) void k_attn(
    const unsigned short* __restrict__ Q,   // [64][2048][64] pre-scaled
    const unsigned short* __restrict__ Kg,  // [64][2048][64]
    const unsigned short* __restrict__ Vt,  // [64][64][2048] key-permuted
    unsigned short* __restrict__ Y)         // [4][2048][1024] bf16
{
    __shared__ alignas(16) unsigned short Ks[2][4096];   // [64 key][64 hd] swz
    __shared__ alignas(16) unsigned short Vs[2][4096];   // [64 hd][64 key] swz
    __shared__ unsigned int Pu[4][32][36];               // packed P per wave
    const int tid = threadIdx.x;
    const int wave = tid >> 6, lane = tid & 63;
    const int lrow = lane & 15, lkg = lane >> 4;
    const int bh = blockIdx.x & 63;              // head id; same head -> same XCD
    const int s = (blockIdx.x >> 6) & 3;
    const int band = blockIdx.x >> 8;            // 0..3
    const int j = (band == 0) ? 15 - s : (band == 1) ? 8 + s : (band == 2) ? 7 - s : s;
    const int qt = 4 * j + wave;                 // this wave's 32-row q tile
    const int q0 = qt * 32;
    const int qmax = q0 + 31;
    const int nt = 2 * j + 2;                    // block-uniform chunk count
    const int b = bh >> 4, hh = bh & 15;

    const unsigned short* Qh = Q + (size_t)bh * 2048 * 64;
    const unsigned short* Kh = Kg + (size_t)bh * 2048 * 64;
    const unsigned short* Vh = Vt + (size_t)bh * 64 * 2048;

    const int srow = tid >> 3;                   // 0..31 (+32 on 2nd issue)
    const int swz = ((tid & 7) ^ (srow & 7)) << 3;
    const unsigned short* gK = Kh + (size_t)srow * 64 + swz;
    const unsigned short* gV = Vh + (size_t)srow * 2048 + swz;
    char* dK0 = (char*)&Ks[0][0] + tid * 16;
    char* dV0 = (char*)&Vs[0][0] + tid * 16;

    bf16x8 aq[2][2];
#pragma unroll
    for (int h = 0; h < 2; ++h)
#pragma unroll
        for (int ks = 0; ks < 2; ++ks)
            aq[h][ks] = *reinterpret_cast<const bf16x8*>(
                &Qh[(size_t)(q0 + h * 16 + lrow) * 64 + ks * 32 + lkg * 8]);

    const bf16x8 ONES = { (short)0x3F80, (short)0x3F80, (short)0x3F80, (short)0x3F80,
                          (short)0x3F80, (short)0x3F80, (short)0x3F80, (short)0x3F80 };

    f32x4 acc[2][4] = {};
    f32x4 accl[2] = {};                          // row sums of P (ones-MFMA)

#define STAGE(kb_, bufn_)                                           \
    do {                                                            \
        const unsigned short* k0_ = gK + (kb_) * 64;                \
        const unsigned short* v0_ = gV + (kb_);                     \
        char* dk_ = dK0 + (bufn_) * 8192;                           \
        char* dv_ = dV0 + (bufn_) * 8192;                           \
        gload16(k0_, dk_);                                          \
        gload16(k0_ + 2048, dk_ + 4096);                            \
        gload16(v0_, dv_);                                          \
        gload16(v0_ + 65536, dv_ + 4096);                           \
    } while (0)

    STAGE(0, 0);
    int buf = 0;

    for (int t = 0; t < nt; ++t) {
        asm volatile("s_waitcnt vmcnt(0)" ::: "memory");
        __builtin_amdgcn_s_barrier();          // buf landed + buf^1 free
        __builtin_amdgcn_sched_barrier(0);
        if (t + 1 < nt) STAGE((t + 1) * 64, buf ^ 1);

        const int kb = t * 64;
        if (kb <= qmax) {                      // wave-uniform causal skip
            const char* kbase = (const char*)&Ks[buf][0];
            const char* vbase = (const char*)&Vs[buf][0];

            // S = Q K^T  (16 MFMAs), K frags from swizzled LDS
            f32x4 s_[2][4] = {};
            __builtin_amdgcn_s_setprio(1);
#pragma unroll
            for (int sub = 0; sub < 4; ++sub) {
                int krow = sub * 16 + lrow;
                bf16x8 kf0 = *reinterpret_cast<const bf16x8*>(
                    kbase + krow * 128 + ((lkg ^ (krow & 7)) << 4));
                bf16x8 kf1 = *reinterpret_cast<const bf16x8*>(
                    kbase + krow * 128 + (((4 + lkg) ^ (krow & 7)) << 4));
                s_[0][sub] = MFMA16(aq[0][0], kf0, s_[0][sub]);
                s_[0][sub] = MFMA16(aq[0][1], kf1, s_[0][sub]);
                s_[1][sub] = MFMA16(aq[1][0], kf0, s_[1][sub]);
                s_[1][sub] = MFMA16(aq[1][1], kf1, s_[1][sub]);
            }
            __builtin_amdgcn_s_setprio(0);

            // causal mask (diagonal-crossing chunks only), then exp2
            const bool need_mask = (kb + 64 > q0);
#pragma unroll
            for (int h = 0; h < 2; ++h)
#pragma unroll
                for (int sub = 0; sub < 4; ++sub)
#pragma unroll
                    for (int r = 0; r < 4; ++r) {
                        float v = s_[h][sub][r];
                        if (need_mask) {
                            int key = kb + sub * 16 + lrow;
                            int q = q0 + h * 16 + lkg * 4 + r;
                            v = (key <= q) ? v : -1e30f;
                        }
                        s_[h][sub][r] = exp2_hw(v);   // masked -> 0
                    }

            // pack P (bf16 pairs, key-permuted order); no VALU row-sum
#pragma unroll
            for (int h = 0; h < 2; ++h) {
                int prow = h * 16 + lkg * 4;
#pragma unroll
                for (int r = 0; r < 4; ++r) {
                    Pu[wave][prow + r][lrow]      = cvt_pk_bf16(s_[h][0][r], s_[h][1][r]);
                    Pu[wave][prow + r][16 + lrow] = cvt_pk_bf16(s_[h][2][r], s_[h][3][r]);
                }
            }

            // P fragments (per-wave, same-wave RAW -> no barrier needed)
            bf16x8 pf[2][2];
#pragma unroll
            for (int h = 0; h < 2; ++h)
#pragma unroll
                for (int kc = 0; kc < 2; ++kc)
                    pf[h][kc] = *reinterpret_cast<const bf16x8*>(
                        &Pu[wave][h * 16 + lrow][kc * 16 + lkg * 4]);

            // PV (16 MFMAs) + row-sum (4 MFMAs), V frags from swizzled LDS
            __builtin_amdgcn_s_setprio(1);
#pragma unroll
            for (int tt = 0; tt < 4; ++tt) {
                int vrow = tt * 16 + lrow;
                bf16x8 vf0 = *reinterpret_cast<const bf16x8*>(
                    vbase + vrow * 128 + ((lkg ^ (vrow & 7)) << 4));
                bf16x8 vf1 = *reinterpret_cast<const bf16x8*>(
                    vbase + vrow * 128 + (((4 + lkg) ^ (vrow & 7)) << 4));
                acc[0][tt] = MFMA16(pf[0][0], vf0, acc[0][tt]);
                acc[0][tt] = MFMA16(pf[0][1], vf1, acc[0][tt]);
                acc[1][tt] = MFMA16(pf[1][0], vf0, acc[1][tt]);
                acc[1][tt] = MFMA16(pf[1][1], vf1, acc[1][tt]);
            }
#pragma unroll
            for (int h = 0; h < 2; ++h) {
                accl[h] = MFMA16(pf[h][0], ONES, accl[h]);
                accl[h] = MFMA16(pf[h][1], ONES, accl[h]);
            }
            __builtin_amdgcn_s_setprio(0);
        }

        buf ^= 1;
    }
#undef STAGE

    // epilogue: normalize (row sums already in accl; cols broadcast), store
#pragma unroll
    for (int h = 0; h < 2; ++h) {
        float inv[4];
#pragma unroll
        for (int r = 0; r < 4; ++r)
            inv[r] = 1.0f / accl[h][r];
#pragma unroll
        for (int t = 0; t < 4; ++t)
#pragma unroll
            for (int r = 0; r < 4; ++r) {
                int q = q0 + h * 16 + lkg * 4 + r;
                size_t idx = ((size_t)b * 2048 + q) * 1024 + hh * 64 + t * 16 + lrow;
                Y[idx] = f2bf(acc[h][t][r] * inv[r]);
            }
    }
}

// ---- GEMM2: Y[8192][1024] @ Wpr -> out fp32 + bias -----------------------
// Ring-3 counted-vmcnt structure + XCD-grouped remap (256 = 8x8x4).
__global__ __launch_bounds__(512, 2) void k_gemm_proj(
    const unsigned short* __restrict__ A,    // [8192][1024] bf16
    const unsigned short* __restrict__ Bt,   // [1024][1024] bf16 (W^T)
    const float* __restrict__ bias,          // [1024]
    float* __restrict__ out)                 // [8192][1024] fp32
{
    constexpr int K = 1024;
    __shared__ alignas(16) char smem[147456];  // ring 3 x 48KB ∪ Ep2 (131.6KB)
    const int tid = threadIdx.x;
    const int wave = tid >> 6, lane = tid & 63;
    const int wr = wave >> 2, wc = wave & 3;
    const int lrow = lane & 15, lkg = lane >> 4;
    const int bid = blockIdx.x;
    const int xcd = bid & 7, sq = bid >> 3;
    const int bm = (xcd * 8 + (sq & 7)) * 128;
    const int bn = (sq >> 3) * 256;

    const int scol = (((tid & 7) ^ ((tid >> 3) & 7)) << 3);
    const int r0 = tid >> 3;
    const unsigned short* gA[2];
    const unsigned short* gB[4];
#pragma unroll
    for (int i = 0; i < 2; ++i)
        gA[i] = A + (size_t)(bm + i * 64 + r0) * K + scol;
#pragma unroll
    for (int i = 0; i < 4; ++i)
        gB[i] = Bt + (size_t)(bn + i * 64 + r0) * K + scol;

    f32x4 acc[4][4] = {};

#define GSTAGE(kt_, slot_)                                          \
    do {                                                            \
        char* ba_ = smem + (slot_) * 49152;                         \
        gload16(gA[0] + (kt_), ba_ + tid * 16);                     \
        gload16(gA[1] + (kt_), ba_ + 8192 + tid * 16);              \
        gload16(gB[0] + (kt_), ba_ + 16384 + tid * 16);             \
        gload16(gB[1] + (kt_), ba_ + 24576 + tid * 16);             \
        gload16(gB[2] + (kt_), ba_ + 32768 + tid * 16);             \
        gload16(gB[3] + (kt_), ba_ + 40960 + tid * 16);             \
    } while (0)

    GSTAGE(0, 0);
    GSTAGE(64, 1);
    int cs = 0;
    for (int t = 0; t < 16; ++t) {
        if (t < 15) asm volatile("s_waitcnt vmcnt(6)" ::: "memory");
        else        asm volatile("s_waitcnt vmcnt(0)" ::: "memory");
        __builtin_amdgcn_s_barrier();
        __builtin_amdgcn_sched_barrier(0);
        if (t + 2 < 16) {
            int ns = cs + 2; if (ns >= 3) ns -= 3;
            GSTAGE((t + 2) * 64, ns);
        }

        const char* Ab = smem + cs * 49152;
        const char* Bb = Ab + 16384;
        bf16x8 af[4][2], bfr[4][2];
#pragma unroll
        for (int m = 0; m < 4; ++m) {
            int R = wr * 64 + m * 16 + lrow;
#pragma unroll
            for (int k = 0; k < 2; ++k)
                af[m][k] = *reinterpret_cast<const bf16x8*>(
                    Ab + R * 128 + (((k * 4 + lkg) ^ (R & 7)) << 4));
        }
#pragma unroll
        for (int n = 0; n < 4; ++n) {
            int R = wc * 64 + n * 16 + lrow;
#pragma unroll
            for (int k = 0; k < 2; ++k)
                bfr[n][k] = *reinterpret_cast<const bf16x8*>(
                    Bb + R * 128 + (((k * 4 + lkg) ^ (R & 7)) << 4));
        }
#pragma unroll
        for (int m = 0; m < 4; ++m)
#pragma unroll
            for (int n = 0; n < 4; ++n) {
                acc[m][n] = MFMA16(af[m][0], bfr[n][0], acc[m][n]);
                acc[m][n] = MFMA16(af[m][1], bfr[n][1], acc[m][n]);
            }
        ++cs; if (cs == 3) cs = 0;
    }
#undef GSTAGE
    __syncthreads();

    // ---- epilogue: single pass, Ep2 [128][257] f32 aliases the ring ----
    float* Ep2 = (float*)smem;
#pragma unroll
    for (int m = 0; m < 4; ++m) {
        int row0 = wr * 64 + m * 16 + lkg * 4;
#pragma unroll
        for (int n = 0; n < 4; ++n) {
            int cl = wc * 64 + n * 16 + lrow;
            float bia = bias[bn + cl];
#pragma unroll
            for (int r = 0; r < 4; ++r)
                Ep2[(row0 + r) * 257 + cl] = acc[m][n][r] + bia;
        }
    }
    __syncthreads();
    const int chunk = tid & 63, rbase = tid >> 6;   // 64 col-chunks x 8 rows
#pragma unroll
    for (int s = 0; s < 16; ++s) {
        int row = s * 8 + rbase;
        float4 v = *reinterpret_cast<const float4*>(&Ep2[row * 257 + chunk * 4]);
        *reinterpret_cast<float4*>(
            &out[(size_t)(bm + row) * 1024 + bn + chunk * 4]) = v;
    }
}

extern "C" void kernel_launch(void* const* d_in, const int* in_sizes, int n_in,
                              void* d_out, int out_size, void* d_ws, size_t ws_size,
                              hipStream_t stream) {
    const float* x    = (const float*)d_in[0];   // [4,2048,1024]
    const float* Wqkv = (const float*)d_in[1];   // [1024,3072]
    const float* bqkv = (const float*)d_in[2];   // [3072]
    const float* Wpr  = (const float*)d_in[3];   // [1024,1024]
    const float* bpr  = (const float*)d_in[4];   // [1024]
    float* out = (float*)d_out;

    char* ws = (char*)d_ws;
    unsigned short* xb  = (unsigned short*)(ws);                  // 16.78 MB (reused as Y)
    unsigned short* Wqt = (unsigned short*)(ws + 16777216);       //  6.29 MB
    unsigned short* Wpt = (unsigned short*)(ws + 23068672);       //  2.10 MB
    unsigned short* Qb  = (unsigned short*)(ws + 25165824);       // 16.78 MB
    unsigned short* Kb  = (unsigned short*)(ws + 41943040);       // 16.78 MB
    unsigned short* Vt  = (unsigned short*)(ws + 58720256);       // 16.78 MB
    unsigned short* Y   = xb;   // xb dead after GEMM1

    k_prep<<<6144, 256, 0, stream>>>(x, xb, Wqkv, Wqt, Wpr, Wpt);
    k_gemm_qkv<<<768, 512, 0, stream>>>(xb, Wqt, bqkv, Qb, Kb, Vt);
    k_attn<<<1024, 256, 0, stream>>>(Qb, Kb, Vt, Y);
    k_gemm_proj<<<256, 512, 0, stream>>>(Y, Wpt, bpr, out);
}